// Round 21
// baseline (145.294 us; speedup 1.0000x reference)
//
#include <hip/hip_runtime.h>
#include <math.h>

#define NEG_SLOPE 0.2f
#define BINSH 8     // 256 nodes per bucket
#define BCAP 6144   // fixed bucket capacity: mean 4092, sigma 64 -> +32 sigma headroom

typedef __attribute__((ext_vector_type(8))) short bf16x8;
typedef __attribute__((ext_vector_type(4))) float f32x4;
typedef __attribute__((ext_vector_type(8))) unsigned short us8;

__device__ inline unsigned short f2b(float f) {  // fp32 -> bf16 RNE
  union { float f; unsigned u; } v; v.f = f;
  unsigned r = v.u + 0x7fffu + ((v.u >> 16) & 1u);
  return (unsigned short)(r >> 16);
}

__device__ inline void gload_lds16(const void* g, void* l) {
  __builtin_amdgcn_global_load_lds(
      (const __attribute__((address_space(1))) void*)g,
      (__attribute__((address_space(3))) void*)l, 16, 0, 0);
}

// ---------------- K1: prepW (blocks 0..127) || binA (remaining blocks) ----------------
// prepW: W[k][n] f32 -> WtBs[n][k] bf16, 16B-chunk XOR-swizzled within each 512B row
// (chunk c -> c ^ (n&31)) so k_work2 stages it LINEARLY via global_load_lds and
// ds_read_b128 with the same XOR is bank-conflict-light.
__launch_bounds__(256)
__global__ void k_work1(const float* __restrict__ W, unsigned short* __restrict__ WtBs,
                        const int* __restrict__ src, const int* __restrict__ dst,
                        int* __restrict__ cursor, unsigned* __restrict__ binned,
                        int E, int NBUK) {
  int bid = blockIdx.x;
  int t = threadIdx.x;
  if (bid < 128) {
    int i = bid * 256 + t;  // 0..32767
    int k = i >> 7, n = i & 127;
    int c = k >> 3, e = k & 7;
    WtBs[n * 256 + ((c ^ (n & 31)) << 3) + e] = f2b(W[(size_t)k * 128 + n]);
    return;
  }
  // binA: bin edges into bucket regions; cursor[] holds within-bucket offsets (memset 0)
  __shared__ int lh[512];
  for (int c = t; c < NBUK; c += 256) lh[c] = 0;
  __syncthreads();
  int base = (bid - 128) * 2048;
  int bq[8], rq[8]; unsigned pq[8];
#pragma unroll
  for (int q = 0; q < 8; ++q) {
    int j = base + q * 256 + t;
    if (j < E) {
      int d = dst[j], s = src[j];
      bq[q] = d >> BINSH;
      pq[q] = ((unsigned)s << 8) | (unsigned)(d & 255);
      rq[q] = atomicAdd(&lh[bq[q]], 1);
    } else bq[q] = -1;
  }
  __syncthreads();
  for (int c = t; c < NBUK; c += 256) { int cnt = lh[c]; if (cnt) lh[c] = atomicAdd(&cursor[c], cnt); }
  __syncthreads();
#pragma unroll
  for (int q = 0; q < 8; ++q)
    if (bq[q] >= 0) binned[(size_t)bq[q] * BCAP + lh[bq[q]] + rq[q]] = pq[q];
}

// ---------------- K2: MFMA gemm (blocks < nGemm) || binB (remaining blocks) --------------
// gemm: 512 threads (8 waves), M-tile 128, BK=64 x 4 steps. B 64KB LDS (staged once).
// A DOUBLE-BUFFERED 2x32KB fp32, staged via global_load_lds with COUNTED s_waitcnt
// vmcnt(4) + raw s_barrier: the next step's 4 loads/thread stay in flight ACROSS the
// barrier while the current step computes (T3+T4) -> memory never idles at a drain.
__launch_bounds__(512, 2)
__global__ void k_work2(const float* __restrict__ x, const unsigned short* __restrict__ WtBs,
                        const float* __restrict__ a_src, const float* __restrict__ a_dst,
                        unsigned short* __restrict__ WhB, float* __restrict__ asrc,
                        float* __restrict__ adst, int N, int nGemm,
                        const unsigned* __restrict__ binned, const int* __restrict__ cursor,
                        int* __restrict__ offsets, int* __restrict__ degs,
                        int* __restrict__ csr) {
  __shared__ __align__(16) unsigned char sbuf[131072];  // Bs 64KB | A dbuf 2x32KB (->Cs)
  int t = threadIdx.x;
  if ((int)blockIdx.x < nGemm) {
    unsigned short* Bs = (unsigned short*)sbuf;   // swizzled [128 n][256 k] bf16
    unsigned short* Cs = (unsigned short*)sbuf;   // [128][136] after K-loop
    int lane = t & 63, wid = t >> 6;              // wid 0..7
    int lr = lane & 15, lh2 = lane >> 4;
    int m0 = blockIdx.x * 128;
    int rowr = wid * 16 + lr;                     // this lane's tile-row (0..127)
    int rsw = rowr & 15;                          // A-read swizzle key

    // ---- stage A step s into buffer buf: 128 rows x 64 f32 = 2048 chunks, 4/thread ----
    auto stageA = [&](int s, int buf) {
#pragma unroll
      for (int i = 0; i < 4; ++i) {
        int chunk = i * 512 + t;
        int row = chunk >> 4, c = chunk & 15;
        int m = m0 + row; if (m >= N) m = N - 1;
        int cs = c ^ (row & 15);  // source-baked swizzle
        gload_lds16(x + (size_t)m * 256 + s * 64 + cs * 4,
                    (char*)sbuf + 65536 + buf * 32768 + (size_t)chunk * 16);
      }
    };

    f32x4 acc[8];
#pragma unroll
    for (int f = 0; f < 8; ++f) acc[f] = (f32x4){0.f, 0.f, 0.f, 0.f};

    // ---- compute step s from buffer buf: 2 k-slices of 32, 16 MFMA per wave ----
    auto compute = [&](int s, int buf) {
      const float* Ab = (const float*)(sbuf + 65536 + buf * 32768);
#pragma unroll
      for (int ks2 = 0; ks2 < 2; ++ks2) {
        int j0 = ks2 * 8 + lh2 * 2;
        f32x4 u0 = *(const f32x4*)(Ab + rowr * 64 + ((j0 ^ rsw) << 2));
        f32x4 u1 = *(const f32x4*)(Ab + rowr * 64 + (((j0 + 1) ^ rsw) << 2));
        bf16x8 a;
        a[0] = (short)f2b(u0[0]); a[1] = (short)f2b(u0[1]);
        a[2] = (short)f2b(u0[2]); a[3] = (short)f2b(u0[3]);
        a[4] = (short)f2b(u1[0]); a[5] = (short)f2b(u1[1]);
        a[6] = (short)f2b(u1[2]); a[7] = (short)f2b(u1[3]);
#pragma unroll
        for (int f = 0; f < 8; ++f) {
          int n = lr + 16 * f;
          bf16x8 b = *(const bf16x8*)(Bs + n * 256 +
                                      (((s * 8 + ks2 * 4 + lh2) ^ (n & 31)) << 3));
          acc[f] = __builtin_amdgcn_mfma_f32_16x16x32_bf16(a, b, acc[f], 0, 0, 0);
        }
      }
    };

    // ---- prologue: B (8 loads/thread) + A steps 0,1 ----
#pragma unroll
    for (int i = 0; i < 8; ++i) {
      int chunk = i * 512 + t;   // 4096 x 16B
      gload_lds16((const char*)WtBs + (size_t)chunk * 16, (char*)sbuf + (size_t)chunk * 16);
    }
    stageA(0, 0);
    stageA(1, 1);
    __builtin_amdgcn_sched_barrier(0);
    asm volatile("s_waitcnt vmcnt(4)" ::: "memory");  // B + A0 landed; A1 in flight
    __builtin_amdgcn_s_barrier();
    __builtin_amdgcn_sched_barrier(0);

    compute(0, 0);
    __builtin_amdgcn_sched_barrier(0);
    __builtin_amdgcn_s_barrier();          // all waves done reading buf0
    stageA(2, 0);
    __builtin_amdgcn_sched_barrier(0);
    asm volatile("s_waitcnt vmcnt(4)" ::: "memory");  // A1 landed; A2 in flight
    __builtin_amdgcn_s_barrier();
    __builtin_amdgcn_sched_barrier(0);

    compute(1, 1);
    __builtin_amdgcn_sched_barrier(0);
    __builtin_amdgcn_s_barrier();          // all waves done reading buf1
    stageA(3, 1);
    __builtin_amdgcn_sched_barrier(0);
    asm volatile("s_waitcnt vmcnt(4)" ::: "memory");  // A2 landed; A3 in flight
    __builtin_amdgcn_s_barrier();
    __builtin_amdgcn_sched_barrier(0);

    compute(2, 0);
    __builtin_amdgcn_sched_barrier(0);
    __builtin_amdgcn_s_barrier();
    asm volatile("s_waitcnt vmcnt(0)" ::: "memory");  // A3 landed
    __builtin_amdgcn_s_barrier();
    __builtin_amdgcn_sched_barrier(0);

    compute(3, 1);

    // ---- fused alpha epilogue. C layout: col = lr+16f, row = wid*16 + lh2*4 + r ----
    float asv[8], adv[8];
#pragma unroll
    for (int f = 0; f < 8; ++f) { asv[f] = a_src[lr + 16 * f]; adv[f] = a_dst[lr + 16 * f]; }
    float as_p[4] = {}, ad_p[4] = {};
#pragma unroll
    for (int f = 0; f < 8; ++f)
#pragma unroll
      for (int r = 0; r < 4; ++r) {
        as_p[r] += acc[f][r] * asv[f];
        ad_p[r] += acc[f][r] * adv[f];
      }
#pragma unroll
    for (int off = 1; off < 16; off <<= 1)
#pragma unroll
      for (int r = 0; r < 4; ++r) {
        as_p[r] += __shfl_xor(as_p[r], off);
        ad_p[r] += __shfl_xor(ad_p[r], off);
      }
    if (lr == 0) {
#pragma unroll
      for (int r = 0; r < 4; ++r) {
        int m = m0 + wid * 16 + lh2 * 4 + r;
        if (m < N) { asrc[m] = as_p[r]; adst[m] = ad_p[r]; }
      }
    }

    // ---- C -> bf16 via [128][136] bounce (reuse sbuf after all LDS reads done) ----
    __syncthreads();
#pragma unroll
    for (int f = 0; f < 8; ++f)
#pragma unroll
      for (int r = 0; r < 4; ++r)
        Cs[(wid * 16 + lh2 * 4 + r) * 136 + lr + 16 * f] = f2b(acc[f][r]);
    __syncthreads();
#pragma unroll
    for (int i = 0; i < 4; ++i) {
      int chunk = i * 512 + t;  // 2048 x 16B
      int rw = chunk >> 4, c8 = chunk & 15;
      int m = m0 + rw;
      if (m < N)
        *(us8*)(WhB + (size_t)m * 128 + c8 * 8) = *(const us8*)(Cs + rw * 136 + c8 * 8);
    }
    return;
  }

  // ---- binB body (512 threads): one block per bucket -> per-node beg/deg + csr ----
  {
    int b = blockIdx.x - nGemm;
    int beg = b * BCAP, end = beg + cursor[b];  // cursor after binA = bucket count
    int node0 = b << BINSH;
    int nn = N - node0; if (nn > 256) nn = 256; if (nn < 0) nn = 0;
    int* ldeg = (int*)sbuf;          // 256 ints
    int* lcur = ldeg + 256;          // 256 ints
    int* wp = lcur + 256;            // 4 ints
    if (t < 256) ldeg[t] = 0;
    __syncthreads();
    for (int j = beg + t; j < end; j += 512) atomicAdd(&ldeg[binned[j] & 255u], 1);
    __syncthreads();
    if (t < 256) {
      int lane = t & 63, wid = t >> 6;
      int v = (t < nn) ? ldeg[t] : 0;
      int incl = v;
#pragma unroll
      for (int off = 1; off < 64; off <<= 1) { int u = __shfl_up(incl, off); if (lane >= off) incl += u; }
      if (lane == 63) wp[wid] = incl;
      lcur[t] = incl - v;  // exclusive within wave (temporarily)
    }
    __syncthreads();
    if (t < 256) {
      int wid = t >> 6;
      int add = 0;
      for (int k = 0; k < wid; ++k) add += wp[k];
      int ex = add + lcur[t];
      int v = (t < nn) ? ldeg[t] : 0;
      if (t < nn) { offsets[node0 + t] = beg + ex; degs[node0 + t] = v; }
      lcur[t] = ex;
    }
    __syncthreads();
    for (int j = beg + t; j < end; j += 512) {
      unsigned e = binned[j];
      int r = atomicAdd(&lcur[e & 255u], 1);
      csr[beg + r] = (int)(e >> 8);
    }
  }
}

// ---------------- per-dst segment softmax + aggregate + ELU ----------------
// 4 nodes per wave; 16 lanes per node; lane owns dims lq*8..lq*8+7 exclusively.
__launch_bounds__(256)
__global__ void k_agg(const int* __restrict__ csr, const int* __restrict__ offsets,
                      const int* __restrict__ degs,
                      const unsigned short* __restrict__ WhB, const float* __restrict__ asrc,
                      const float* __restrict__ adst, float* __restrict__ out, int N) {
  int gt = blockIdx.x * blockDim.x + threadIdx.x;
  int wave = gt >> 6;
  int lane = gt & 63;
  int lq = lane & 15;       // dim slice within node
  int g = lane >> 4;        // node subgroup 0..3
  int node = wave * 4 + g;
  if (node >= N) return;
  int beg = offsets[node];
  int end = beg + degs[node];
  float ad = adst[node];
  float acc[8] = {};
  float psum = 0.f;
  for (int chunk = beg; chunk < end; chunk += 16) {
    int j = chunk + lq;
    float p = 0.f; int mys = 0;
    if (j < end) {
      mys = csr[j];
      float e = asrc[mys] + ad;
      e = e > 0.f ? e : NEG_SLOPE * e;
      p = __expf(e);  // |e| <~ 10, softmax shift-invariant
    }
    psum += p;
#pragma unroll
    for (int tt = 0; tt < 8; ++tt) {    // half 1: 8 loads in flight
      float pt = __shfl(p, tt, 16);     // pt==0 for tail edges -> exact no-op FMAs
      int st = __shfl(mys, tt, 16);
      uint4 v = *(const uint4*)(WhB + (size_t)(unsigned)st * 128u + lq * 8);
      acc[0] = fmaf(pt, __uint_as_float(v.x << 16), acc[0]);
      acc[1] = fmaf(pt, __uint_as_float(v.x & 0xffff0000u), acc[1]);
      acc[2] = fmaf(pt, __uint_as_float(v.y << 16), acc[2]);
      acc[3] = fmaf(pt, __uint_as_float(v.y & 0xffff0000u), acc[3]);
      acc[4] = fmaf(pt, __uint_as_float(v.z << 16), acc[4]);
      acc[5] = fmaf(pt, __uint_as_float(v.z & 0xffff0000u), acc[5]);
      acc[6] = fmaf(pt, __uint_as_float(v.w << 16), acc[6]);
      acc[7] = fmaf(pt, __uint_as_float(v.w & 0xffff0000u), acc[7]);
    }
    __builtin_amdgcn_sched_barrier(0);  // cap live load-destinations at 8
#pragma unroll
    for (int tt = 8; tt < 16; ++tt) {   // half 2
      float pt = __shfl(p, tt, 16);
      int st = __shfl(mys, tt, 16);
      uint4 v = *(const uint4*)(WhB + (size_t)(unsigned)st * 128u + lq * 8);
      acc[0] = fmaf(pt, __uint_as_float(v.x << 16), acc[0]);
      acc[1] = fmaf(pt, __uint_as_float(v.x & 0xffff0000u), acc[1]);
      acc[2] = fmaf(pt, __uint_as_float(v.y << 16), acc[2]);
      acc[3] = fmaf(pt, __uint_as_float(v.y & 0xffff0000u), acc[3]);
      acc[4] = fmaf(pt, __uint_as_float(v.z << 16), acc[4]);
      acc[5] = fmaf(pt, __uint_as_float(v.z & 0xffff0000u), acc[5]);
      acc[6] = fmaf(pt, __uint_as_float(v.w << 16), acc[6]);
      acc[7] = fmaf(pt, __uint_as_float(v.w & 0xffff0000u), acc[7]);
    }
  }
  // one denom reduction per node
  psum += __shfl_xor(psum, 1);
  psum += __shfl_xor(psum, 2);
  psum += __shfl_xor(psum, 4);
  psum += __shfl_xor(psum, 8);
  float inv = 1.f / (psum + 1e-16f);  // deg==0: acc=0 -> out=0
  size_t obase = (size_t)node * 128 + lq * 8;
  float r[8];
#pragma unroll
  for (int i = 0; i < 8; ++i) {
    float o = acc[i] * inv;
    r[i] = o > 0.f ? o : __expf(o) - 1.f;
  }
  // nontemporal: out (51 MB) is never re-read; keep it out of L2/L3 so Wh stays cached
  f32x4 lo = {r[0], r[1], r[2], r[3]};
  f32x4 hi = {r[4], r[5], r[6], r[7]};
  __builtin_nontemporal_store(lo, (f32x4*)(out + obase));
  __builtin_nontemporal_store(hi, (f32x4*)(out + obase + 4));
}

extern "C" void kernel_launch(void* const* d_in, const int* in_sizes, int n_in,
                              void* d_out, int out_size, void* d_ws, size_t ws_size,
                              hipStream_t stream) {
  const float* x = (const float*)d_in[0];
  const int* ei = (const int*)d_in[1];
  const float* W = (const float*)d_in[2];
  const float* a_src = (const float*)d_in[3];
  const float* a_dst = (const float*)d_in[4];
  int N = in_sizes[0] / 256;
  int E = in_sizes[1] / 2;
  const int* src = ei;
  const int* dst = ei + E;
  float* out = (float*)d_out;
  int NBUK = (N + 255) >> BINSH;
  size_t REG = (size_t)NBUK * BCAP;  // gapped bucket region (slots)

  // workspace layout
  unsigned short* WhB = (unsigned short*)d_ws;            // N*128 bf16
  unsigned* binned = (unsigned*)(WhB + (size_t)N * 128);  // REG packed edges
  int* csr = (int*)(binned + REG);                        // REG
  float* asrc = (float*)(csr + REG);                      // N
  float* adst = asrc + N;                                 // N
  unsigned short* WtBs = (unsigned short*)(adst + N);     // 32768 bf16 (swizzled layout)
  int* cursor = (int*)(WtBs + 32768);                     // NBUK
  int* offsets = cursor + NBUK;                           // N
  int* degs = offsets + N;                                // N

  int nBinA = (E + 2047) / 2048;
  int nGemm = (N + 127) / 128;

  hipMemsetAsync(cursor, 0, (size_t)NBUK * sizeof(int), stream);
  k_work1<<<128 + nBinA, 256, 0, stream>>>(W, WtBs, src, dst, cursor, binned, E, NBUK);
  k_work2<<<nGemm + NBUK, 512, 0, stream>>>(x, WtBs, a_src, a_dst, WhB, asrc, adst, N, nGemm,
                                            binned, cursor, offsets, degs, csr);
  k_agg<<<(N + 15) / 16, 256, 0, stream>>>(csr, offsets, degs, WhB, asrc, adst, out, N);
}

// Round 22
// 135.757 us; speedup vs baseline: 1.0703x; 1.0703x over previous
//
#include <hip/hip_runtime.h>
#include <math.h>

#define NEG_SLOPE 0.2f
#define BINSH 8     // 256 nodes per bucket
#define BCAP 6144   // fixed bucket capacity: mean 4092, sigma 64 -> +32 sigma headroom

typedef __attribute__((ext_vector_type(8))) short bf16x8;
typedef __attribute__((ext_vector_type(4))) float f32x4;
typedef __attribute__((ext_vector_type(8))) unsigned short us8;

__device__ inline unsigned short f2b(float f) {  // fp32 -> bf16 RNE
  union { float f; unsigned u; } v; v.f = f;
  unsigned r = v.u + 0x7fffu + ((v.u >> 16) & 1u);
  return (unsigned short)(r >> 16);
}

__device__ inline void gload_lds16(const void* g, void* l) {
  __builtin_amdgcn_global_load_lds(
      (const __attribute__((address_space(1))) void*)g,
      (__attribute__((address_space(3))) void*)l, 16, 0, 0);
}

// ---------------- K1: prepW (blocks 0..127) || binA (remaining blocks) ----------------
// prepW: W[k][n] f32 -> WtBs[n][k] bf16, 16B-chunk XOR-swizzled within each 512B row
// (chunk c -> c ^ (n&31)) so k_work2 stages it LINEARLY via global_load_lds and
// ds_read_b128 with the same XOR is bank-conflict-light.
__launch_bounds__(256)
__global__ void k_work1(const float* __restrict__ W, unsigned short* __restrict__ WtBs,
                        const int* __restrict__ src, const int* __restrict__ dst,
                        int* __restrict__ cursor, unsigned* __restrict__ binned,
                        int E, int NBUK) {
  int bid = blockIdx.x;
  int t = threadIdx.x;
  if (bid < 128) {
    int i = bid * 256 + t;  // 0..32767
    int k = i >> 7, n = i & 127;
    int c = k >> 3, e = k & 7;
    WtBs[n * 256 + ((c ^ (n & 31)) << 3) + e] = f2b(W[(size_t)k * 128 + n]);
    return;
  }
  // binA: bin edges into bucket regions; cursor[] holds within-bucket offsets (memset 0)
  __shared__ int lh[512];
  for (int c = t; c < NBUK; c += 256) lh[c] = 0;
  __syncthreads();
  int base = (bid - 128) * 2048;
  int bq[8], rq[8]; unsigned pq[8];
#pragma unroll
  for (int q = 0; q < 8; ++q) {
    int j = base + q * 256 + t;
    if (j < E) {
      int d = dst[j], s = src[j];
      bq[q] = d >> BINSH;
      pq[q] = ((unsigned)s << 8) | (unsigned)(d & 255);
      rq[q] = atomicAdd(&lh[bq[q]], 1);
    } else bq[q] = -1;
  }
  __syncthreads();
  for (int c = t; c < NBUK; c += 256) { int cnt = lh[c]; if (cnt) lh[c] = atomicAdd(&cursor[c], cnt); }
  __syncthreads();
#pragma unroll
  for (int q = 0; q < 8; ++q)
    if (bq[q] >= 0) binned[(size_t)bq[q] * BCAP + lh[bq[q]] + rq[q]] = pq[q];
}

// ---------------- K2: MFMA gemm (blocks < nGemm) || binB (remaining blocks) --------------
// gemm: 512 threads, 8 waves, M-tile 256. Per wave: 2 row-frags, acc[2][8] (~88 regs total
// incl acc in the unified file). B staged once to 64KB LDS -> 2 blocks/CU = 16 waves/CU.
// C written back in two half-passes through a [128][136] bounce.
__launch_bounds__(512, 4)
__global__ void k_work2(const float* __restrict__ x, const unsigned short* __restrict__ WtBs,
                        const float* __restrict__ a_src, const float* __restrict__ a_dst,
                        unsigned short* __restrict__ WhB, float* __restrict__ asrc,
                        float* __restrict__ adst, int N, int nGemm,
                        const unsigned* __restrict__ binned, const int* __restrict__ cursor,
                        int* __restrict__ offsets, int* __restrict__ degs,
                        int* __restrict__ csr) {
  __shared__ __align__(16) unsigned char sbuf[65536];  // union: Bs 64KB | Cs 34KB | binB
  int t = threadIdx.x;
  if ((int)blockIdx.x < nGemm) {
    unsigned short* Bs = (unsigned short*)sbuf;   // swizzled [128][256] bf16
    unsigned short* Cs = (unsigned short*)sbuf;   // [128][136] after K-loop
    int lane = t & 63, wid = t >> 6;              // wid 0..7
    int lr = lane & 15, lh2 = lane >> 4;
    int m0 = blockIdx.x * 256;

    // ---- stage B: linear 64KB copy, 8 gload_lds per thread (no VGPR dests) ----
#pragma unroll
    for (int i = 0; i < 8; ++i) {
      int chunk = i * 512 + t;   // 4096 x 16B
      gload_lds16((const float*)WtBs + (size_t)chunk * 4, (char*)sbuf + (size_t)chunk * 16);
    }

    int row0 = m0 + wid * 32 + lr;
    int row1 = row0 + 16;
    int r0c = row0 < N ? row0 : N - 1;
    int r1c = row1 < N ? row1 : N - 1;
    const float* xp0 = x + (size_t)r0c * 256 + lh2 * 8;
    const float* xp1 = x + (size_t)r1c * 256 + lh2 * 8;

    f32x4 acc[2][8];
#pragma unroll
    for (int rf = 0; rf < 2; ++rf)
#pragma unroll
      for (int f = 0; f < 8; ++f) acc[rf][f] = (f32x4){0.f, 0.f, 0.f, 0.f};

    __syncthreads();  // vmcnt(0) drain: B resident in LDS

#pragma unroll
    for (int ks = 0; ks < 8; ++ks) {
      float4 u0 = *(const float4*)(xp0 + ks * 32);
      float4 u1 = *(const float4*)(xp0 + ks * 32 + 4);
      float4 v0 = *(const float4*)(xp1 + ks * 32);
      float4 v1 = *(const float4*)(xp1 + ks * 32 + 4);
      bf16x8 a0, a1;
      a0[0] = (short)f2b(u0.x); a0[1] = (short)f2b(u0.y);
      a0[2] = (short)f2b(u0.z); a0[3] = (short)f2b(u0.w);
      a0[4] = (short)f2b(u1.x); a0[5] = (short)f2b(u1.y);
      a0[6] = (short)f2b(u1.z); a0[7] = (short)f2b(u1.w);
      a1[0] = (short)f2b(v0.x); a1[1] = (short)f2b(v0.y);
      a1[2] = (short)f2b(v0.z); a1[3] = (short)f2b(v0.w);
      a1[4] = (short)f2b(v1.x); a1[5] = (short)f2b(v1.y);
      a1[6] = (short)f2b(v1.z); a1[7] = (short)f2b(v1.w);
#pragma unroll
      for (int f = 0; f < 8; ++f) {
        int n = lr + 16 * f;
        bf16x8 b = *(const bf16x8*)(Bs + n * 256 + (((ks * 4 + lh2) ^ (n & 31)) << 3));
        acc[0][f] = __builtin_amdgcn_mfma_f32_16x16x32_bf16(a0, b, acc[0][f], 0, 0, 0);
        acc[1][f] = __builtin_amdgcn_mfma_f32_16x16x32_bf16(a1, b, acc[1][f], 0, 0, 0);
      }
    }

    // fused alpha epilogue. C layout: col=lr+16f, row = wid*32 + rf*16 + lh2*4 + r
    float asv[8], adv[8];
#pragma unroll
    for (int f = 0; f < 8; ++f) { asv[f] = a_src[lr + 16 * f]; adv[f] = a_dst[lr + 16 * f]; }
    float as_p[2][4] = {}, ad_p[2][4] = {};
#pragma unroll
    for (int rf = 0; rf < 2; ++rf)
#pragma unroll
      for (int f = 0; f < 8; ++f)
#pragma unroll
        for (int r = 0; r < 4; ++r) {
          as_p[rf][r] += acc[rf][f][r] * asv[f];
          ad_p[rf][r] += acc[rf][f][r] * adv[f];
        }
#pragma unroll
    for (int off = 1; off < 16; off <<= 1)
#pragma unroll
      for (int rf = 0; rf < 2; ++rf)
#pragma unroll
        for (int r = 0; r < 4; ++r) {
          as_p[rf][r] += __shfl_xor(as_p[rf][r], off);
          ad_p[rf][r] += __shfl_xor(ad_p[rf][r], off);
        }
    if (lr == 0) {
#pragma unroll
      for (int rf = 0; rf < 2; ++rf)
#pragma unroll
        for (int r = 0; r < 4; ++r) {
          int m = m0 + wid * 32 + rf * 16 + lh2 * 4 + r;
          if (m < N) { asrc[m] = as_p[rf][r]; adst[m] = ad_p[rf][r]; }
        }
    }

    // C -> bf16 in two half-passes through [128][136] bounce (reuse sbuf after B reads)
#pragma unroll
    for (int h = 0; h < 2; ++h) {
      __syncthreads();  // h=0: B reads done; h=1: previous copy-out done
      if ((wid >> 2) == h) {
#pragma unroll
        for (int rf = 0; rf < 2; ++rf)
#pragma unroll
          for (int f = 0; f < 8; ++f)
#pragma unroll
            for (int r = 0; r < 4; ++r)
              Cs[((wid & 3) * 32 + rf * 16 + lh2 * 4 + r) * 136 + lr + 16 * f] =
                  f2b(acc[rf][f][r]);
      }
      __syncthreads();
#pragma unroll
      for (int i = 0; i < 4; ++i) {
        int chunk = i * 512 + t;  // 2048 x 16B
        int row = chunk >> 4, c8 = chunk & 15;
        int m = m0 + h * 128 + row;
        if (m < N)
          *(us8*)(WhB + (size_t)m * 128 + c8 * 8) = *(const us8*)(Cs + row * 136 + c8 * 8);
      }
    }
    return;
  }

  // ---- binB body (512 threads): one block per bucket -> per-node beg/deg + csr ----
  {
    int b = blockIdx.x - nGemm;
    int beg = b * BCAP, end = beg + cursor[b];  // cursor after binA = bucket count
    int node0 = b << BINSH;
    int nn = N - node0; if (nn > 256) nn = 256; if (nn < 0) nn = 0;
    int* ldeg = (int*)sbuf;          // 256 ints
    int* lcur = ldeg + 256;          // 256 ints
    int* wp = lcur + 256;            // 4 ints
    if (t < 256) ldeg[t] = 0;
    __syncthreads();
    for (int j = beg + t; j < end; j += 512) atomicAdd(&ldeg[binned[j] & 255u], 1);
    __syncthreads();
    if (t < 256) {
      int lane = t & 63, wid = t >> 6;
      int v = (t < nn) ? ldeg[t] : 0;
      int incl = v;
#pragma unroll
      for (int off = 1; off < 64; off <<= 1) { int u = __shfl_up(incl, off); if (lane >= off) incl += u; }
      if (lane == 63) wp[wid] = incl;
      lcur[t] = incl - v;  // exclusive within wave (temporarily)
    }
    __syncthreads();
    if (t < 256) {
      int wid = t >> 6;
      int add = 0;
      for (int k = 0; k < wid; ++k) add += wp[k];
      int ex = add + lcur[t];
      int v = (t < nn) ? ldeg[t] : 0;
      if (t < nn) { offsets[node0 + t] = beg + ex; degs[node0 + t] = v; }
      lcur[t] = ex;
    }
    __syncthreads();
    for (int j = beg + t; j < end; j += 512) {
      unsigned e = binned[j];
      int r = atomicAdd(&lcur[e & 255u], 1);
      csr[beg + r] = (int)(e >> 8);
    }
  }
}

// ---------------- per-dst segment softmax + aggregate + ELU ----------------
// 4 nodes per wave; 16 lanes per node; lane owns dims lq*8..lq*8+7 exclusively.
__launch_bounds__(256)
__global__ void k_agg(const int* __restrict__ csr, const int* __restrict__ offsets,
                      const int* __restrict__ degs,
                      const unsigned short* __restrict__ WhB, const float* __restrict__ asrc,
                      const float* __restrict__ adst, float* __restrict__ out, int N) {
  int gt = blockIdx.x * blockDim.x + threadIdx.x;
  int wave = gt >> 6;
  int lane = gt & 63;
  int lq = lane & 15;       // dim slice within node
  int g = lane >> 4;        // node subgroup 0..3
  int node = wave * 4 + g;
  if (node >= N) return;
  int beg = offsets[node];
  int end = beg + degs[node];
  float ad = adst[node];
  float acc[8] = {};
  float psum = 0.f;
  for (int chunk = beg; chunk < end; chunk += 16) {
    int j = chunk + lq;
    float p = 0.f; int mys = 0;
    if (j < end) {
      mys = csr[j];
      float e = asrc[mys] + ad;
      e = e > 0.f ? e : NEG_SLOPE * e;
      p = __expf(e);  // |e| <~ 10, softmax shift-invariant
    }
    psum += p;
#pragma unroll
    for (int tt = 0; tt < 8; ++tt) {    // half 1: 8 loads in flight
      float pt = __shfl(p, tt, 16);     // pt==0 for tail edges -> exact no-op FMAs
      int st = __shfl(mys, tt, 16);
      uint4 v = *(const uint4*)(WhB + (size_t)(unsigned)st * 128u + lq * 8);
      acc[0] = fmaf(pt, __uint_as_float(v.x << 16), acc[0]);
      acc[1] = fmaf(pt, __uint_as_float(v.x & 0xffff0000u), acc[1]);
      acc[2] = fmaf(pt, __uint_as_float(v.y << 16), acc[2]);
      acc[3] = fmaf(pt, __uint_as_float(v.y & 0xffff0000u), acc[3]);
      acc[4] = fmaf(pt, __uint_as_float(v.z << 16), acc[4]);
      acc[5] = fmaf(pt, __uint_as_float(v.z & 0xffff0000u), acc[5]);
      acc[6] = fmaf(pt, __uint_as_float(v.w << 16), acc[6]);
      acc[7] = fmaf(pt, __uint_as_float(v.w & 0xffff0000u), acc[7]);
    }
    __builtin_amdgcn_sched_barrier(0);  // cap live load-destinations at 8
#pragma unroll
    for (int tt = 8; tt < 16; ++tt) {   // half 2
      float pt = __shfl(p, tt, 16);
      int st = __shfl(mys, tt, 16);
      uint4 v = *(const uint4*)(WhB + (size_t)(unsigned)st * 128u + lq * 8);
      acc[0] = fmaf(pt, __uint_as_float(v.x << 16), acc[0]);
      acc[1] = fmaf(pt, __uint_as_float(v.x & 0xffff0000u), acc[1]);
      acc[2] = fmaf(pt, __uint_as_float(v.y << 16), acc[2]);
      acc[3] = fmaf(pt, __uint_as_float(v.y & 0xffff0000u), acc[3]);
      acc[4] = fmaf(pt, __uint_as_float(v.z << 16), acc[4]);
      acc[5] = fmaf(pt, __uint_as_float(v.z & 0xffff0000u), acc[5]);
      acc[6] = fmaf(pt, __uint_as_float(v.w << 16), acc[6]);
      acc[7] = fmaf(pt, __uint_as_float(v.w & 0xffff0000u), acc[7]);
    }
  }
  // one denom reduction per node
  psum += __shfl_xor(psum, 1);
  psum += __shfl_xor(psum, 2);
  psum += __shfl_xor(psum, 4);
  psum += __shfl_xor(psum, 8);
  float inv = 1.f / (psum + 1e-16f);  // deg==0: acc=0 -> out=0
  size_t obase = (size_t)node * 128 + lq * 8;
  float r[8];
#pragma unroll
  for (int i = 0; i < 8; ++i) {
    float o = acc[i] * inv;
    r[i] = o > 0.f ? o : __expf(o) - 1.f;
  }
  // nontemporal: out (51 MB) is never re-read; keep it out of L2/L3 so Wh stays cached
  f32x4 lo = {r[0], r[1], r[2], r[3]};
  f32x4 hi = {r[4], r[5], r[6], r[7]};
  __builtin_nontemporal_store(lo, (f32x4*)(out + obase));
  __builtin_nontemporal_store(hi, (f32x4*)(out + obase + 4));
}

extern "C" void kernel_launch(void* const* d_in, const int* in_sizes, int n_in,
                              void* d_out, int out_size, void* d_ws, size_t ws_size,
                              hipStream_t stream) {
  const float* x = (const float*)d_in[0];
  const int* ei = (const int*)d_in[1];
  const float* W = (const float*)d_in[2];
  const float* a_src = (const float*)d_in[3];
  const float* a_dst = (const float*)d_in[4];
  int N = in_sizes[0] / 256;
  int E = in_sizes[1] / 2;
  const int* src = ei;
  const int* dst = ei + E;
  float* out = (float*)d_out;
  int NBUK = (N + 255) >> BINSH;
  size_t REG = (size_t)NBUK * BCAP;  // gapped bucket region (slots)

  // workspace layout
  unsigned short* WhB = (unsigned short*)d_ws;            // N*128 bf16
  unsigned* binned = (unsigned*)(WhB + (size_t)N * 128);  // REG packed edges
  int* csr = (int*)(binned + REG);                        // REG
  float* asrc = (float*)(csr + REG);                      // N
  float* adst = asrc + N;                                 // N
  unsigned short* WtBs = (unsigned short*)(adst + N);     // 32768 bf16 (swizzled layout)
  int* cursor = (int*)(WtBs + 32768);                     // NBUK
  int* offsets = cursor + NBUK;                           // N
  int* degs = offsets + N;                                // N

  int nBinA = (E + 2047) / 2048;
  int nGemm = (N + 255) / 256;

  hipMemsetAsync(cursor, 0, (size_t)NBUK * sizeof(int), stream);
  k_work1<<<128 + nBinA, 256, 0, stream>>>(W, WtBs, src, dst, cursor, binned, E, NBUK);
  k_work2<<<nGemm + NBUK, 512, 0, stream>>>(x, WtBs, a_src, a_dst, WhB, asrc, adst, N, nGemm,
                                            binned, cursor, offsets, degs, csr);
  k_agg<<<(N + 15) / 16, 256, 0, stream>>>(csr, offsets, degs, WhB, asrc, adst, out, N);
}